// Round 1
// baseline (181.273 us; speedup 1.0000x reference)
//
#include <hip/hip_runtime.h>

// LCSA: dilated local-window self-attention.
// B=2, L=1024, D=512, H=8, HEAD_W=64, KERNEL=16, dilations {1,1,2,2,4,4,8,8},
// MODE=forward -> src(l,k) = l - (15-k)*dil, zero-padded outside [0,L).
//
// R11: gemm_bf16 rebuilt as a pipelined 8-wave kernel (T3+T4+T5 stack):
//   - 128x256 tile, BK=64 split in two 32-wide k-chunks, double-buffered LDS
//     (96 KB), 8 waves (2M x 4N), 16x16x32 MFMA, same XOR-chunk swizzle as
//     R6 (bank-conflict-free, sources pre-swizzled by cvt_swz).
//   - raw s_barrier + counted s_waitcnt vmcnt(6): stage of tile t+2 is
//     issued inside tile t's compute phases, right after the lgkmcnt(0)+
//     barrier that retires all reads of the region being overwritten;
//     loads stay in flight across barriers (never vmcnt(0) until t>=6).
//   - s_setprio(1) around each 16-MFMA cluster.
//   - grid 1056 blocks with bijective XCD-chunked remap (1056 = 8*132):
//     16 consecutive logical tiles share one 256-col B-panel per XCD L2.
//   R10 structure measured 57.3us @ MfmaUtil 24% (per-iter latency exposed
//   by the __syncthreads vmcnt(0) drain); predicted ~30us here.
// attn_bf16: TWO-PHASE register-resident gather (unchanged).
// gemm_out:  out = attnb*Wo^T + bo (unchanged).
// Fallback: round-1 fp32 path (8 MB ws).

#define BD 2
#define LL 1024
#define DM 512
#define HH 8
#define KT 16
#define HW 64

#define NQKV 16896          // 512 q + 8192 k + 8192 v

typedef unsigned short u16;
typedef unsigned int u32;
typedef __bf16 bf16x8 __attribute__((ext_vector_type(8)));
typedef float f32x4 __attribute__((ext_vector_type(4)));
typedef unsigned short ushort4v __attribute__((ext_vector_type(4)));
typedef unsigned short ushort8v __attribute__((ext_vector_type(8)));

__constant__ int c_dil[8] = {1, 1, 2, 2, 4, 4, 8, 8};

__device__ __forceinline__ float bf2f(u16 u) {
    return __builtin_bit_cast(float, (u32)u << 16);
}
__device__ __forceinline__ u16 f2bf(float f) {   // round-to-nearest-even
    u32 u = __builtin_bit_cast(u32, f);
    return (u16)((u + 0x7fffu + ((u >> 16) & 1u)) >> 16);
}

// async global->LDS, 16 B per lane; lds dest must be (uniform base + lane*16)
__device__ __forceinline__ void gl_lds16(const u16* g, u16* l) {
    __builtin_amdgcn_global_load_lds(
        (__attribute__((address_space(1))) void*)g,
        (__attribute__((address_space(3))) void*)l, 16, 0, 0);
}

// raw workgroup barrier with compiler memory fences on both sides
// (s_barrier alone carries no compiler-level memory ordering)
__device__ __forceinline__ void bar() {
    asm volatile("" ::: "memory");
    __builtin_amdgcn_s_barrier();
    asm volatile("" ::: "memory");
}

// ===========================================================================
// Fused qkv projection GEMM, pipelined.
// C(2048 x NQKV bf16) = x(2048x512) * [Wq|Wk|Wv]^T + bias.
// 128x256 tile, BK=64 (2 k-chunks of 32), 8 waves (64x64 out each),
// double-buffered LDS, counted vmcnt, setprio. Grid 1056 x 512thr.
//
// Pipeline invariants (3 gl_lds16 per k-chunk stage):
//   prologue issues tiles 0,1 (12 loads), waits vmcnt(6)  -> tile0 landed
//   tile t sub-phase ks: reads buf[t&1][ks]; lgkmcnt(0)+barrier retires
//     reads block-wide; THEN stage(t+2, ks) may overwrite that region.
//   end-of-tile vmcnt(6) leaves only this tile's 2 staged chunks (6 loads)
//     in flight -> tile t+1 fully landed before its first ds_read.
//   t==6 stages nothing, so drain vmcnt(0) there; t==7 needs no wait.
// ===========================================================================
__global__ __launch_bounds__(512, 2) void gemm_bf16(
    const u16* __restrict__ A, const u16* __restrict__ Bm,
    const float* __restrict__ bq, const float* __restrict__ bk,
    const float* __restrict__ bv, u16* __restrict__ C)
{
    __shared__ u16 As[2][2][128 * 32];   // [buf][kchunk][row*32 + swz]  32 KB
    __shared__ u16 Bs[2][2][256 * 32];   //                               64 KB

    // bijective XCD-chunked remap: 1056 = 8 XCDs * 132 contiguous tiles
    const int bid = blockIdx.x;
    const int wg  = (bid & 7) * 132 + (bid >> 3);
    const int m0  = (wg & 15) << 7;      // 16 m-tiles of 128
    const int n0  = (wg >> 4) << 8;      // 66 n-tiles of 256 (B-panel shared
                                         //  by 16 consecutive wg -> L2 reuse)

    const int tid  = threadIdx.x;
    const int wid  = tid >> 6, lane = tid & 63;
    const int wm   = wid >> 2;           // 0..1  (64-row band)
    const int wn   = wid & 3;            // 0..3  (64-col band)
    const int lr   = lane & 15, qg = lane >> 4;
    const int ksw  = ((qg ^ ((lr >> 1) & 3)) << 3);   // swizzled chunk

    const int r0 = tid >> 2;             // staging row 0..127
    const int c8 = (tid & 3) << 3;       // staging k-offset (elements)
    const u16* Ag = A  + (size_t)(m0 + r0) * DM + c8;
    const u16* Bg = Bm + (size_t)(n0 + r0) * DM + c8;
    u16* lA = &As[0][0][0] + tid * 8;
    u16* lB = &Bs[0][0][0] + tid * 8;

    f32x4 acc[4][4];
#pragma unroll
    for (int i = 0; i < 4; ++i)
#pragma unroll
        for (int j = 0; j < 4; ++j) acc[i][j] = (f32x4){0.f, 0.f, 0.f, 0.f};

    // stage one 32-wide k-chunk of tile t2 into buffer c: 3 loads/thread
#define STAGE(t2, ks, c) do {                                              \
        const int ko_ = ((t2) << 6) + ((ks) << 5);                         \
        gl_lds16(Ag + ko_, lA + ((c) * 2 + (ks)) * 4096);                  \
        gl_lds16(Bg + ko_, lB + ((c) * 2 + (ks)) * 8192);                  \
        gl_lds16(Bg + ko_ + (size_t)128 * DM,                              \
                 lB + ((c) * 2 + (ks)) * 8192 + 4096);                     \
    } while (0)

    STAGE(0, 0, 0); STAGE(0, 1, 0);      // tile 0 -> buf 0
    STAGE(1, 0, 1); STAGE(1, 1, 1);      // tile 1 -> buf 1
    asm volatile("s_waitcnt vmcnt(6)" ::: "memory");   // tile 0 landed
    bar();

#pragma unroll
    for (int t = 0; t < 8; ++t) {
        const int c = t & 1;
#pragma unroll
        for (int ks = 0; ks < 2; ++ks) {
            bf16x8 af[4], bfr[4];
#pragma unroll
            for (int m = 0; m < 4; ++m)
                af[m] = *(const bf16x8*)
                    &As[c][ks][((wm << 6) + (m << 4) + lr) * 32 + ksw];
#pragma unroll
            for (int n = 0; n < 4; ++n)
                bfr[n] = *(const bf16x8*)
                    &Bs[c][ks][((wn << 6) + (n << 4) + lr) * 32 + ksw];
            // retire this region's reads block-wide before overwriting it
            asm volatile("s_waitcnt lgkmcnt(0)" ::: "memory");
            bar();
            if (t < 6) STAGE(t + 2, ks, c);
            __builtin_amdgcn_s_setprio(1);
#pragma unroll
            for (int m = 0; m < 4; ++m)
#pragma unroll
                for (int n = 0; n < 4; ++n)
                    acc[m][n] = __builtin_amdgcn_mfma_f32_16x16x32_bf16(
                        af[m], bfr[n], acc[m][n], 0, 0, 0);
            __builtin_amdgcn_s_setprio(0);
        }
        // tile t+1 must be resident before next iteration's ds_reads
        if (t < 6)       asm volatile("s_waitcnt vmcnt(6)" ::: "memory");
        else if (t == 6) asm volatile("s_waitcnt vmcnt(0)" ::: "memory");
        bar();
    }
#undef STAGE

    // bias region is tile-uniform (n-tiles 0..1 q, 2..33 k, 34..65 v)
    const float* bias; int cb;
    if      (n0 <  512) { bias = bq; cb = 0;    }
    else if (n0 < 8704) { bias = bk; cb = 512;  }
    else                { bias = bv; cb = 8704; }

    // C row = m0 + wm*64 + 16m + 4qg + r, col = n0 + wn*64 + 16n + lr
#pragma unroll
    for (int m = 0; m < 4; ++m) {
        const int rowb = m0 + (wm << 6) + (m << 4) + (qg << 2);
#pragma unroll
        for (int n = 0; n < 4; ++n) {
            const int col = n0 + (wn << 6) + (n << 4) + lr;
            const float bs = bias[col - cb];
#pragma unroll
            for (int r = 0; r < 4; ++r)
                C[(size_t)(rowb + r) * NQKV + col] = f2bf(acc[m][n][r] + bs);
        }
    }
}

// ===========================================================================
// Output projection: out(2048x512 fp32) = attnb(2048x512 swz) * Wo^T(512x512
// swz) + bo. 64x64 tiles, grid (8,32) = 256 blocks, 4 waves (16x64 each).
// ===========================================================================
__global__ __launch_bounds__(256, 4) void gemm_out(
    const u16* __restrict__ A, const u16* __restrict__ Bm,
    const float* __restrict__ bias, float* __restrict__ C)
{
    __shared__ u16 As[64 * 32];
    __shared__ u16 Bs[64 * 32];

    const int tid  = threadIdx.x;
    const int wave = tid >> 6, lane = tid & 63;
    const int m0 = blockIdx.y << 6, n0 = blockIdx.x << 6;
    const int r0 = tid >> 2, cc = (tid & 3) << 3;
    const int mw = wave << 4;           // wave's 16-row band
    const int lr = lane & 15, qg = lane >> 4;
    const int ksw = ((qg ^ ((lr >> 1) & 3)) << 3);

    const u16* Ag = A  + (size_t)(m0 + r0) * DM + cc;
    const u16* Bg = Bm + (size_t)(n0 + r0) * DM + cc;
    u16* lA = &As[0] + tid * 8;
    u16* lB = &Bs[0] + tid * 8;

    f32x4 acc[4];
#pragma unroll
    for (int j = 0; j < 4; ++j) acc[j] = (f32x4){0.f, 0.f, 0.f, 0.f};

    for (int k0 = 0; k0 < DM; k0 += 32) {
        gl_lds16(Ag + k0, lA);
        gl_lds16(Bg + k0, lB);
        __syncthreads();
        bf16x8 af = *(const bf16x8*)&As[(mw + lr) * 32 + ksw];
#pragma unroll
        for (int j = 0; j < 4; ++j) {
            bf16x8 bfr = *(const bf16x8*)&Bs[((j << 4) + lr) * 32 + ksw];
            acc[j] = __builtin_amdgcn_mfma_f32_16x16x32_bf16(af, bfr, acc[j], 0, 0, 0);
        }
        __syncthreads();
    }

    // C row = m0+mw+4qg+r, col = n0+16j+lr
#pragma unroll
    for (int j = 0; j < 4; ++j) {
        const int col = n0 + (j << 4) + lr;
        const float bs = bias[col];
#pragma unroll
        for (int r = 0; r < 4; ++r)
            C[(size_t)(m0 + mw + (qg << 2) + r) * DM + col] = acc[j][r] + bs;
    }
}

// ===========================================================================
// fp32 -> bf16 + swizzle. One thread per 8-elem chunk: 32B read, 16B write,
// both coalesced (the XOR permutes chunks within a 64B line).
// Chunks (row*64): x 131072 | [Wq|Wk|Wv] 1081344 | Wo 32768
// Total 1245184 = 4864 blocks x 256.
// ===========================================================================
__global__ void cvt_swz(const float* __restrict__ x,  const float* __restrict__ Wq,
                        const float* __restrict__ Wk, const float* __restrict__ Wv,
                        const float* __restrict__ Wo,
                        u16* __restrict__ xb, u16* __restrict__ wb,
                        u16* __restrict__ wob)
{
    const int i = blockIdx.x * 256 + threadIdx.x;
    const float* src; u16* dst; int t;
    if (i < 131072) {
        t = i;
        src = x;  dst = xb;
    } else if (i < 1212416) {
        t = i - 131072;
        const int row = t >> 6;
        if      (row <  512) src = Wq;
        else if (row < 8704) src = Wk - (size_t)512 * DM;
        else                 src = Wv - (size_t)8704 * DM;
        dst = wb;
    } else {
        t = i - 1212416;
        src = Wo; dst = wob;
    }
    const int row = t >> 6;              // 64 chunks per row
    const int c8  = t & 63;              // output chunk within row
    const int s   = (row >> 1) & 3;
    const int oc  = (c8 & ~3) | ((c8 & 3) ^ s);   // source chunk
    const float* p = src + (size_t)row * DM + (oc << 3);
    float4 v0 = *(const float4*)p;
    float4 v1 = *(const float4*)(p + 4);
    ushort8v o = { f2bf(v0.x), f2bf(v0.y), f2bf(v0.z), f2bf(v0.w),
                   f2bf(v1.x), f2bf(v1.y), f2bf(v1.z), f2bf(v1.w) };
    *(ushort8v*)(dst + (size_t)row * DM + (c8 << 3)) = o;
}

// ===========================================================================
// attention gather, TWO-PHASE register-resident.
// 256 thr = 32 l's x 8 o-groups, grid = B*H*(L/32) = 512.
// Phase 1: all 16 k-row loads issued back-to-back (independent addresses,
//          max loads-in-flight), 16 logits via 3x shfl_xor each.
// Softmax entirely in registers.
// Phase 2: all 16 v-row loads issued, weighted accumulate.
// (256,4) -> 128-VGPR budget: kr[16] payload is 64 VGPRs; R9's (256,8)
// forced VGPR=32 and serialized the stream (65us @ 28% HBM).
// ===========================================================================
__global__ __launch_bounds__(256, 4) void attn_bf16(
    const u16* __restrict__ qkv,    // (B*L, NQKV) bf16
    const float* __restrict__ bk,   // (H,K,64) fp32
    const float* __restrict__ bv,
    u16* __restrict__ attnb)        // (B,L,512) bf16 swizzled
{
    const int tid = threadIdx.x;
    const int j  = tid & 7;          // o-group (8 o's)
    const int ll = tid >> 3;         // 0..31
    const int bid = blockIdx.x;
    const int h = bid & 7;
    const int t = (bid >> 3) & 31;
    const int b = bid >> 8;
    const int l = (t << 5) + ll;
    const int dil = c_dil[h];

    const int hko = h * (KT * HW);   // head offset within k/v region
    const size_t rowbase = (size_t)(b * LL) * NQKV + hko + (j << 3);

    float qf[8];
    {
        ushort8v qv = *(const ushort8v*)(qkv + (size_t)(b * LL + l) * NQKV
                                         + h * HW + (j << 3));
#pragma unroll
        for (int z = 0; z < 8; ++z) qf[z] = bf2f(qv[z]);
    }

    // ---- phase 1: all k loads in flight, then logits ----
    ushort8v kr[KT];
#pragma unroll
    for (int k = 0; k < KT; ++k) {
        const int src = l - (KT - 1 - k) * dil;
        if (src >= 0)
            kr[k] = *(const ushort8v*)(qkv + rowbase + (size_t)src * NQKV
                                       + 512 + k * HW);
    }

    float lg[KT];
#pragma unroll
    for (int k = 0; k < KT; ++k) {
        const int src = l - (KT - 1 - k) * dil;
        float p = 0.f;
        if (src >= 0) {
#pragma unroll
            for (int z = 0; z < 8; ++z) p += qf[z] * bf2f(kr[k][z]);
        } else {
            const float* bkp = bk + hko + k * HW + (j << 3);
#pragma unroll
            for (int z = 0; z < 8; ++z) p += qf[z] * bkp[z];
        }
        p += __shfl_xor(p, 1);
        p += __shfl_xor(p, 2);
        p += __shfl_xor(p, 4);
        lg[k] = p;
    }

    // ---- softmax in registers ----
    float m = lg[0];
#pragma unroll
    for (int k = 1; k < KT; ++k) m = fmaxf(m, lg[k]);
    float s = 0.f;
#pragma unroll
    for (int k = 0; k < KT; ++k) { lg[k] = __expf(lg[k] - m); s += lg[k]; }
    const float inv = 1.f / s;

    // ---- phase 2: all v loads in flight, weighted accumulate ----
    ushort8v vr[KT];
#pragma unroll
    for (int k = 0; k < KT; ++k) {
        const int src = l - (KT - 1 - k) * dil;
        if (src >= 0)
            vr[k] = *(const ushort8v*)(qkv + rowbase + (size_t)src * NQKV
                                       + 8704 + k * HW);
    }

    float acc[8];
#pragma unroll
    for (int z = 0; z < 8; ++z) acc[z] = 0.f;
#pragma unroll
    for (int k = 0; k < KT; ++k) {
        const int src = l - (KT - 1 - k) * dil;
        const float sc = lg[k] * inv;
        if (src >= 0) {
#pragma unroll
            for (int z = 0; z < 8; ++z) acc[z] = fmaf(sc, bf2f(vr[k][z]), acc[z]);
        } else {
            const float* bvp = bv + hko + k * HW + (j << 3);
#pragma unroll
            for (int z = 0; z < 8; ++z) acc[z] = fmaf(sc, bvp[z], acc[z]);
        }
    }

    ushort8v o;
#pragma unroll
    for (int z = 0; z < 8; ++z) o[z] = f2bf(acc[z] * 0.125f);
    const int row = b * LL + l;
    const int k8 = h * 8 + j;
    const int sw = ((k8 & 3) ^ ((l >> 1) & 3)) << 3;
    *(ushort8v*)(attnb + (size_t)row * DM + ((k8 >> 2) << 5) + sw) = o;
}

// ===========================================================================
// ------------------- round-1 fp32 fallback (small ws) ----------------------
// ===========================================================================
__global__ __launch_bounds__(256, 2) void gemm_nt_bias(
    const float* __restrict__ A, const float* __restrict__ Bm,
    const float* __restrict__ bias, float* __restrict__ C,
    int M, int N, int Kd)
{
    __shared__ float As[16][68];
    __shared__ float Bs[16][68];
    const int tid = threadIdx.x;
    const int tx = tid & 15, ty = tid >> 4;
    const int r0 = blockIdx.y << 6, c0 = blockIdx.x << 6;
    const int lr = tid >> 2, k4 = (tid & 3) << 2;
    const float* Ap = A  + (size_t)(r0 + lr) * Kd + k4;
    const float* Bp = Bm + (size_t)(c0 + lr) * Kd + k4;
    float acc[4][4];
#pragma unroll
    for (int i = 0; i < 4; ++i)
#pragma unroll
        for (int j = 0; j < 4; ++j) acc[i][j] = 0.f;
    for (int d0 = 0; d0 < Kd; d0 += 16) {
        float4 av = *(const float4*)(Ap + d0);
        float4 bv = *(const float4*)(Bp + d0);
        As[k4 + 0][lr] = av.x; As[k4 + 1][lr] = av.y;
        As[k4 + 2][lr] = av.z; As[k4 + 3][lr] = av.w;
        Bs[k4 + 0][lr] = bv.x; Bs[k4 + 1][lr] = bv.y;
        Bs[k4 + 2][lr] = bv.z; Bs[k4 + 3][lr] = bv.w;
        __syncthreads();
#pragma unroll
        for (int dd = 0; dd < 16; ++dd) {
            float4 a4 = *(const float4*)&As[dd][ty << 2];
            float4 b4 = *(const float4*)&Bs[dd][tx << 2];
            float ar[4] = {a4.x, a4.y, a4.z, a4.w};
            float br[4] = {b4.x, b4.y, b4.z, b4.w};
#pragma unroll
            for (int i = 0; i < 4; ++i)
#pragma unroll
                for (int j = 0; j < 4; ++j)
                    acc[i][j] = fmaf(ar[i], br[j], acc[i][j]);
        }
        __syncthreads();
    }
#pragma unroll
    for (int i = 0; i < 4; ++i) {
        float4 o;
        const int c = c0 + (tx << 2);
        o.x = acc[i][0] + bias[c + 0];
        o.y = acc[i][1] + bias[c + 1];
        o.z = acc[i][2] + bias[c + 2];
        o.w = acc[i][3] + bias[c + 3];
        *(float4*)&C[(size_t)(r0 + (ty << 2) + i) * N + c] = o;
    }
}

__device__ __forceinline__ void tile_gemm_f32(
    const float* __restrict__ xb, int src, bool ok,
    const float* __restrict__ wrow,
    int lr, int k4, int tx, int ty,
    float (&As)[16][68], float (&Ws)[16][68], float (&acc)[4][4])
{
#pragma unroll
    for (int i = 0; i < 4; ++i)
#pragma unroll
        for (int j = 0; j < 4; ++j) acc[i][j] = 0.f;
    const float* xrow = xb + (size_t)(ok ? src : 0) * DM + k4;
    for (int d0 = 0; d0 < DM; d0 += 16) {
        float4 av = make_float4(0.f, 0.f, 0.f, 0.f);
        if (ok) av = *(const float4*)(xrow + d0);
        float4 wv = *(const float4*)(wrow + d0);
        As[k4 + 0][lr] = av.x; As[k4 + 1][lr] = av.y;
        As[k4 + 2][lr] = av.z; As[k4 + 3][lr] = av.w;
        Ws[k4 + 0][lr] = wv.x; Ws[k4 + 1][lr] = wv.y;
        Ws[k4 + 2][lr] = wv.z; Ws[k4 + 3][lr] = wv.w;
        __syncthreads();
#pragma unroll
        for (int dd = 0; dd < 16; ++dd) {
            float4 a4 = *(const float4*)&As[dd][ty << 2];
            float4 b4 = *(const float4*)&Ws[dd][tx << 2];
            float ar[4] = {a4.x, a4.y, a4.z, a4.w};
            float br[4] = {b4.x, b4.y, b4.z, b4.w};
#pragma unroll
            for (int i = 0; i < 4; ++i)
#pragma unroll
                for (int j = 0; j < 4; ++j)
                    acc[i][j] = fmaf(ar[i], br[j], acc[i][j]);
        }
        __syncthreads();
    }
}

__global__ __launch_bounds__(256, 2) void attn_kernel(
    const float* __restrict__ x, const float* __restrict__ q,
    const float* __restrict__ Wk, const float* __restrict__ bk,
    const float* __restrict__ Wv, const float* __restrict__ bv,
    float* __restrict__ attn)
{
    __shared__ float As[16][68];
    __shared__ float Ws[16][68];
    __shared__ float qs[64][68];
    __shared__ float lg[64][17];
    __shared__ float red[64][17];
    const int tid = threadIdx.x;
    const int tx = tid & 15, ty = tid >> 4;
    const int bid = blockIdx.x;
    const int h = bid & 7, t = (bid >> 3) & 15, b = bid >> 7;
    const int l0 = t << 6;
    const int dil = c_dil[h];
    const int lr = tid >> 2, k4 = (tid & 3) << 2;
    for (int i = tid; i < 64 * 16; i += 256) {
        int l = i >> 4, o4 = (i & 15) << 2;
        float4 v = *(const float4*)&q[((size_t)(b * LL + l0 + l) * HH + h) * HW + o4];
        *(float4*)&qs[l][o4] = v;
    }
    const float* xb  = x  + (size_t)b * LL * DM;
    const float* Wkh = Wk + (size_t)h * KT * HW * DM;
    const float* Wvh = Wv + (size_t)h * KT * HW * DM;
    const float* bkh = bk + h * KT * HW;
    const float* bvh = bv + h * KT * HW;
    float acc[4][4];
    for (int kk = 0; kk < KT; ++kk) {
        const int src = l0 + lr - (KT - 1 - kk) * dil;
        const bool ok = (src >= 0) && (src < LL);
        tile_gemm_f32(xb, src, ok, Wkh + (size_t)(kk * HW + lr) * DM + k4,
                      lr, k4, tx, ty, As, Ws, acc);
        const float* bkp = bkh + kk * HW + (tx << 2);
#pragma unroll
        for (int i = 0; i < 4; ++i) {
            float p = 0.f;
#pragma unroll
            for (int j = 0; j < 4; ++j)
                p += (acc[i][j] + bkp[j]) * qs[(ty << 2) + i][(tx << 2) + j];
            red[(ty << 2) + i][tx] = p;
        }
        __syncthreads();
        if (tid < 64) {
            float s = 0.f;
#pragma unroll
            for (int u = 0; u < 16; ++u) s += red[tid][u];
            lg[tid][kk] = s;
        }
        __syncthreads();
    }
    if (tid < 64) {
        float m = lg[tid][0];
#pragma unroll
        for (int u = 1; u < KT; ++u) m = fmaxf(m, lg[tid][u]);
        float s = 0.f;
#pragma unroll
        for (int u = 0; u < KT; ++u) {
            float e = expf(lg[tid][u] - m);
            lg[tid][u] = e; s += e;
        }
        float inv = 1.f / s;
#pragma unroll
        for (int u = 0; u < KT; ++u) lg[tid][u] *= inv;
    }
    __syncthreads();
    float vacc[4][4];
#pragma unroll
    for (int i = 0; i < 4; ++i)
#pragma unroll
        for (int j = 0; j < 4; ++j) vacc[i][j] = 0.f;
    for (int kk = 0; kk < KT; ++kk) {
        const int src = l0 + lr - (KT - 1 - kk) * dil;
        const bool ok = (src >= 0) && (src < LL);
        tile_gemm_f32(xb, src, ok, Wvh + (size_t)(kk * HW + lr) * DM + k4,
                      lr, k4, tx, ty, As, Ws, acc);
        const float* bvp = bvh + kk * HW + (tx << 2);
#pragma unroll
        for (int i = 0; i < 4; ++i) {
            float sc = lg[(ty << 2) + i][kk];
#pragma unroll
            for (int j = 0; j < 4; ++j)
                vacc[i][j] = fmaf(sc, acc[i][j] + bvp[j], vacc[i][j]);
        }
    }
#pragma unroll
    for (int i = 0; i < 4; ++i) {
        float4 o;
        o.x = vacc[i][0] * 0.125f;
        o.y = vacc[i][1] * 0.125f;
        o.z = vacc[i][2] * 0.125f;
        o.w = vacc[i][3] * 0.125f;
        *(float4*)&attn[((size_t)(b * LL + l0 + (ty << 2) + i) * HH + h) * HW + (tx << 2)] = o;
    }
}

// ===========================================================================
extern "C" void kernel_launch(void* const* d_in, const int* in_sizes, int n_in,
                              void* d_out, int out_size, void* d_ws, size_t ws_size,
                              hipStream_t stream)
{
    const float* x  = (const float*)d_in[0];
    const float* Wq = (const float*)d_in[1];
    const float* bq = (const float*)d_in[2];
    const float* Wk = (const float*)d_in[3];
    const float* bk = (const float*)d_in[4];
    const float* Wv = (const float*)d_in[5];
    const float* bv = (const float*)d_in[6];
    const float* Wo = (const float*)d_in[7];
    const float* bo = (const float*)d_in[8];
    float* out = (float*)d_out;

    const int M = BD * LL;  // 2048

    // ws layout (ushort elements) for the fast path
    const size_t N_X   = (size_t)BD * LL * DM;            //  1,048,576
    const size_t N_WB  = (size_t)NQKV * DM;               //  8,650,752
    const size_t N_WO  = (size_t)DM * DM;                 //    262,144
    const size_t N_QKV = (size_t)M * NQKV;                // 34,603,008
    const size_t NEED  = (N_X + N_WB + N_WO + N_QKV + N_X) * 2;

    if (ws_size >= NEED) {
        u16* xb    = (u16*)d_ws;
        u16* wb    = xb    + N_X;      // [Wq|Wk|Wv] swizzled, 16896 x 512
        u16* wob   = wb    + N_WB;
        u16* qkv   = wob   + N_WO;     // natural row-major 2048 x 16896
        u16* attnb = qkv   + N_QKV;

        cvt_swz<<<4864, 256, 0, stream>>>(x, Wq, Wk, Wv, Wo, xb, wb, wob);

        // qkv = x * [Wq|Wk|Wv]^T + bias (pipelined 8-wave, 1056 blocks)
        gemm_bf16<<<dim3(1056), 512, 0, stream>>>(
            xb, wb, bq, bk, bv, qkv);

        // two-phase register-resident gather -> attnb (swizzled)
        attn_bf16<<<BD * HH * (LL / 32), 256, 0, stream>>>(
            qkv, bk, bv, attnb);

        // out = attnb * Wo^T + bo -> fp32
        gemm_out<<<dim3(8, 32), 256, 0, stream>>>(attnb, wob, bo, out);
    } else {
        // fp32 fallback (round-1 path, 8 MB ws)
        float* qws = (float*)d_ws;
        float* aws = qws + (size_t)BD * LL * HH * HW;
        gemm_nt_bias<<<dim3((HH * HW) / 64, M / 64), 256, 0, stream>>>(
            x, Wq, bq, qws, M, HH * HW, DM);
        attn_kernel<<<BD * HH * (LL / 64), 256, 0, stream>>>(
            x, qws, Wk, bk, Wv, bv, aws);
        gemm_nt_bias<<<dim3(DM / 64, M / 64), 256, 0, stream>>>(
            aws, Wo, bo, out, M, DM, HH * HW);
    }
}

// Round 3
// 171.928 us; speedup vs baseline: 1.0544x; 1.0544x over previous
//
#include <hip/hip_runtime.h>

// LCSA: dilated local-window self-attention.
// B=2, L=1024, D=512, H=8, HEAD_W=64, KERNEL=16, dilations {1,1,2,2,4,4,8,8},
// MODE=forward -> src(l,k) = l - (15-k)*dil, zero-padded outside [0,L).
//
// R12 (resubmit; prior round hit a container-infra failure, never measured):
//   gemm_bf16 = R10/R6 geometry (128x128 tile, BK=32, 256 thr, 4 blk/CU)
//   + minimum 2-phase double-buffer (T3 recipe): stage tile t+1 at TOP of
//   iter t into buf^1, one __syncthreads (vmcnt drain) at END. Keeps the
//   4-block/CU implicit overlap that R11's 96KB/1-blk/CU lockstep destroyed
//   (R11: 67.9us @ 17% occ; R10: 57.3us @ 31% occ, drain-before-compute).
//   Same transformation on gemm_out (was 1 blk/CU, fully latency-exposed).
// attn_bf16: TWO-PHASE register-resident gather (unchanged, R10).
// cvt_swz:   fp32->bf16 + per-row XOR chunk swizzle (unchanged, R10).
// Fallback:  round-1 fp32 path (8 MB ws).

#define BD 2
#define LL 1024
#define DM 512
#define HH 8
#define KT 16
#define HW 64

#define NQKV 16896          // 512 q + 8192 k + 8192 v

typedef unsigned short u16;
typedef unsigned int u32;
typedef __bf16 bf16x8 __attribute__((ext_vector_type(8)));
typedef float f32x4 __attribute__((ext_vector_type(4)));
typedef unsigned short ushort4v __attribute__((ext_vector_type(4)));
typedef unsigned short ushort8v __attribute__((ext_vector_type(8)));

__constant__ int c_dil[8] = {1, 1, 2, 2, 4, 4, 8, 8};

__device__ __forceinline__ float bf2f(u16 u) {
    return __builtin_bit_cast(float, (u32)u << 16);
}
__device__ __forceinline__ u16 f2bf(float f) {   // round-to-nearest-even
    u32 u = __builtin_bit_cast(u32, f);
    return (u16)((u + 0x7fffu + ((u >> 16) & 1u)) >> 16);
}

// async global->LDS, 16 B per lane; lds dest must be (uniform base + lane*16)
__device__ __forceinline__ void gl_lds16(const u16* g, u16* l) {
    __builtin_amdgcn_global_load_lds(
        (__attribute__((address_space(1))) void*)g,
        (__attribute__((address_space(3))) void*)l, 16, 0, 0);
}

// ===========================================================================
// Fused qkv projection GEMM, 2-phase double-buffered.
// C(2048 x NQKV bf16) = x(2048x512) * [Wq|Wk|Wv]^T + bias.
// 128x128 tile, BK=32, 4 waves (64x64 each), 16x16x32 MFMA, swizzled A/B,
// LDS 32KB (2 bufs) -> 4 blocks/CU. Grid 136x16, pad-exit.
//
// Per iter: issue 4 gl_lds16 for tile t+1 into buf^1 (no wait), ds_read
// buf, 16 MFMA, then ONE __syncthreads (drains vmcnt: t+1 landed; also
// retires all waves' ds_reads of buf before next iter overwrites it).
// ===========================================================================
__global__ __launch_bounds__(256, 4) void gemm_bf16(
    const u16* __restrict__ A, const u16* __restrict__ Bm,
    const float* __restrict__ bq, const float* __restrict__ bk,
    const float* __restrict__ bv, u16* __restrict__ C)
{
    const int m0 = blockIdx.y << 7;
    const int n0 = blockIdx.x << 7;
    if (n0 >= NQKV) return;             // pad tiles (block-uniform)

    __shared__ u16 As[2][128 * 32];     // 2 x 8 KB
    __shared__ u16 Bs[2][128 * 32];     // 2 x 8 KB

    const int tid  = threadIdx.x;
    const int wave = tid >> 6, lane = tid & 63;
    const int r0 = tid >> 2;            // staging row 0..63 (round 0)
    const int cc = (tid & 3) << 3;      // staging k-offset (elements)
    const int mw = (wave >> 1) << 6;
    const int nw = (wave & 1) << 6;
    const int lr = lane & 15;
    const int qg = lane >> 4;
    const int ksw = ((qg ^ ((lr >> 1) & 3)) << 3);   // swizzled chunk

    const u16* Ag = A  + (size_t)(m0 + r0) * DM + cc;
    const u16* Bg = Bm + (size_t)(n0 + r0) * DM + cc;
    u16* lA = &As[0][0] + tid * 8;
    u16* lB = &Bs[0][0] + tid * 8;

    // stage k-chunk at element offset ko into buffer c (4 loads/thread)
#define STG(ko, c) do {                                                    \
        gl_lds16(Ag + (ko),                  lA + (c) * 4096);             \
        gl_lds16(Ag + (ko) + (size_t)64*DM,  lA + (c) * 4096 + 2048);      \
        gl_lds16(Bg + (ko),                  lB + (c) * 4096);             \
        gl_lds16(Bg + (ko) + (size_t)64*DM,  lB + (c) * 4096 + 2048);      \
    } while (0)

    f32x4 acc[4][4];
#pragma unroll
    for (int i = 0; i < 4; ++i)
#pragma unroll
        for (int j = 0; j < 4; ++j) acc[i][j] = (f32x4){0.f, 0.f, 0.f, 0.f};

    STG(0, 0);
    __syncthreads();                    // tile 0 resident

#pragma unroll
    for (int kc = 0; kc < 16; ++kc) {
        const int cur = kc & 1;
        if (kc < 15) STG((kc + 1) << 5, cur ^ 1);   // prefetch next tile

        bf16x8 af[4], bfr[4];
#pragma unroll
        for (int i = 0; i < 4; ++i)
            af[i] = *(const bf16x8*)&As[cur][(mw + (i << 4) + lr) * 32 + ksw];
#pragma unroll
        for (int j = 0; j < 4; ++j)
            bfr[j] = *(const bf16x8*)&Bs[cur][(nw + (j << 4) + lr) * 32 + ksw];
#pragma unroll
        for (int i = 0; i < 4; ++i)
#pragma unroll
            for (int j = 0; j < 4; ++j)
                acc[i][j] = __builtin_amdgcn_mfma_f32_16x16x32_bf16(
                    af[i], bfr[j], acc[i][j], 0, 0, 0);

        __syncthreads();                // drains vmcnt: tile kc+1 landed;
                                        // all reads of buf[cur] retired
    }
#undef STG

    // bias region is tile-uniform (tiles 0..3 q, 4..67 k, 68..131 v)
    const float* bias; int cb;
    if      (n0 <  512) { bias = bq; cb = 0;    }
    else if (n0 < 8704) { bias = bk; cb = 512;  }
    else                { bias = bv; cb = 8704; }

    // C row = m0+mw+16i+4qg+r, col = n0+nw+16j+lr
#pragma unroll
    for (int i = 0; i < 4; ++i) {
        const int rowb = m0 + mw + (i << 4) + (qg << 2);
#pragma unroll
        for (int j = 0; j < 4; ++j) {
            const int col = n0 + nw + (j << 4) + lr;
            const float bs = bias[col - cb];
#pragma unroll
            for (int r = 0; r < 4; ++r)
                C[(size_t)(rowb + r) * NQKV + col] = f2bf(acc[i][j][r] + bs);
        }
    }
}

// ===========================================================================
// Output projection: out(2048x512 fp32) = attnb(2048x512 swz) * Wo^T(512x512
// swz) + bo. 64x64 tiles, grid (8,32) = 256 blocks, 4 waves (16x64 each).
// 2-phase double-buffered like gemm_bf16 (was fully latency-exposed at
// 1 blk/CU x 16 serial iterations).
// ===========================================================================
__global__ __launch_bounds__(256, 4) void gemm_out(
    const u16* __restrict__ A, const u16* __restrict__ Bm,
    const float* __restrict__ bias, float* __restrict__ C)
{
    __shared__ u16 As[2][64 * 32];      // 2 x 4 KB
    __shared__ u16 Bs[2][64 * 32];      // 2 x 4 KB

    const int tid  = threadIdx.x;
    const int wave = tid >> 6, lane = tid & 63;
    const int m0 = blockIdx.y << 6, n0 = blockIdx.x << 6;
    const int r0 = tid >> 2, cc = (tid & 3) << 3;
    const int mw = wave << 4;           // wave's 16-row band
    const int lr = lane & 15, qg = lane >> 4;
    const int ksw = ((qg ^ ((lr >> 1) & 3)) << 3);

    const u16* Ag = A  + (size_t)(m0 + r0) * DM + cc;
    const u16* Bg = Bm + (size_t)(n0 + r0) * DM + cc;
    u16* lA = &As[0][0] + tid * 8;
    u16* lB = &Bs[0][0] + tid * 8;

#define STG(ko, c) do {                                                    \
        gl_lds16(Ag + (ko), lA + (c) * 2048);                              \
        gl_lds16(Bg + (ko), lB + (c) * 2048);                              \
    } while (0)

    f32x4 acc[4];
#pragma unroll
    for (int j = 0; j < 4; ++j) acc[j] = (f32x4){0.f, 0.f, 0.f, 0.f};

    STG(0, 0);
    __syncthreads();

#pragma unroll
    for (int kc = 0; kc < 16; ++kc) {
        const int cur = kc & 1;
        if (kc < 15) STG((kc + 1) << 5, cur ^ 1);

        bf16x8 af = *(const bf16x8*)&As[cur][(mw + lr) * 32 + ksw];
#pragma unroll
        for (int j = 0; j < 4; ++j) {
            bf16x8 bfr = *(const bf16x8*)&Bs[cur][((j << 4) + lr) * 32 + ksw];
            acc[j] = __builtin_amdgcn_mfma_f32_16x16x32_bf16(af, bfr, acc[j], 0, 0, 0);
        }
        __syncthreads();
    }
#undef STG

    // C row = m0+mw+4qg+r, col = n0+16j+lr
#pragma unroll
    for (int j = 0; j < 4; ++j) {
        const int col = n0 + (j << 4) + lr;
        const float bs = bias[col];
#pragma unroll
        for (int r = 0; r < 4; ++r)
            C[(size_t)(m0 + mw + (qg << 2) + r) * DM + col] = acc[j][r] + bs;
    }
}

// ===========================================================================
// fp32 -> bf16 + swizzle. One thread per 8-elem chunk: 32B read, 16B write,
// both coalesced (the XOR permutes chunks within a 64B line).
// Chunks (row*64): x 131072 | [Wq|Wk|Wv] 1081344 | Wo 32768
// Total 1245184 = 4864 blocks x 256.
// ===========================================================================
__global__ void cvt_swz(const float* __restrict__ x,  const float* __restrict__ Wq,
                        const float* __restrict__ Wk, const float* __restrict__ Wv,
                        const float* __restrict__ Wo,
                        u16* __restrict__ xb, u16* __restrict__ wb,
                        u16* __restrict__ wob)
{
    const int i = blockIdx.x * 256 + threadIdx.x;
    const float* src; u16* dst; int t;
    if (i < 131072) {
        t = i;
        src = x;  dst = xb;
    } else if (i < 1212416) {
        t = i - 131072;
        const int row = t >> 6;
        if      (row <  512) src = Wq;
        else if (row < 8704) src = Wk - (size_t)512 * DM;
        else                 src = Wv - (size_t)8704 * DM;
        dst = wb;
    } else {
        t = i - 1212416;
        src = Wo; dst = wob;
    }
    const int row = t >> 6;              // 64 chunks per row
    const int c8  = t & 63;              // output chunk within row
    const int s   = (row >> 1) & 3;
    const int oc  = (c8 & ~3) | ((c8 & 3) ^ s);   // source chunk
    const float* p = src + (size_t)row * DM + (oc << 3);
    float4 v0 = *(const float4*)p;
    float4 v1 = *(const float4*)(p + 4);
    ushort8v o = { f2bf(v0.x), f2bf(v0.y), f2bf(v0.z), f2bf(v0.w),
                   f2bf(v1.x), f2bf(v1.y), f2bf(v1.z), f2bf(v1.w) };
    *(ushort8v*)(dst + (size_t)row * DM + (c8 << 3)) = o;
}

// ===========================================================================
// attention gather, TWO-PHASE register-resident.
// 256 thr = 32 l's x 8 o-groups, grid = B*H*(L/32) = 512.
// Phase 1: all 16 k-row loads issued back-to-back (independent addresses,
//          max loads-in-flight), 16 logits via 3x shfl_xor each.
// Softmax entirely in registers.
// Phase 2: all 16 v-row loads issued, weighted accumulate.
// (256,4) -> 128-VGPR budget: kr[16] payload is 64 VGPRs; R9's (256,8)
// forced VGPR=32 and serialized the stream (65us @ 28% HBM).
// ===========================================================================
__global__ __launch_bounds__(256, 4) void attn_bf16(
    const u16* __restrict__ qkv,    // (B*L, NQKV) bf16
    const float* __restrict__ bk,   // (H,K,64) fp32
    const float* __restrict__ bv,
    u16* __restrict__ attnb)        // (B,L,512) bf16 swizzled
{
    const int tid = threadIdx.x;
    const int j  = tid & 7;          // o-group (8 o's)
    const int ll = tid >> 3;         // 0..31
    const int bid = blockIdx.x;
    const int h = bid & 7;
    const int t = (bid >> 3) & 31;
    const int b = bid >> 8;
    const int l = (t << 5) + ll;
    const int dil = c_dil[h];

    const int hko = h * (KT * HW);   // head offset within k/v region
    const size_t rowbase = (size_t)(b * LL) * NQKV + hko + (j << 3);

    float qf[8];
    {
        ushort8v qv = *(const ushort8v*)(qkv + (size_t)(b * LL + l) * NQKV
                                         + h * HW + (j << 3));
#pragma unroll
        for (int z = 0; z < 8; ++z) qf[z] = bf2f(qv[z]);
    }

    // ---- phase 1: all k loads in flight, then logits ----
    ushort8v kr[KT];
#pragma unroll
    for (int k = 0; k < KT; ++k) {
        const int src = l - (KT - 1 - k) * dil;
        if (src >= 0)
            kr[k] = *(const ushort8v*)(qkv + rowbase + (size_t)src * NQKV
                                       + 512 + k * HW);
    }

    float lg[KT];
#pragma unroll
    for (int k = 0; k < KT; ++k) {
        const int src = l - (KT - 1 - k) * dil;
        float p = 0.f;
        if (src >= 0) {
#pragma unroll
            for (int z = 0; z < 8; ++z) p += qf[z] * bf2f(kr[k][z]);
        } else {
            const float* bkp = bk + hko + k * HW + (j << 3);
#pragma unroll
            for (int z = 0; z < 8; ++z) p += qf[z] * bkp[z];
        }
        p += __shfl_xor(p, 1);
        p += __shfl_xor(p, 2);
        p += __shfl_xor(p, 4);
        lg[k] = p;
    }

    // ---- softmax in registers ----
    float m = lg[0];
#pragma unroll
    for (int k = 1; k < KT; ++k) m = fmaxf(m, lg[k]);
    float s = 0.f;
#pragma unroll
    for (int k = 0; k < KT; ++k) { lg[k] = __expf(lg[k] - m); s += lg[k]; }
    const float inv = 1.f / s;

    // ---- phase 2: all v loads in flight, weighted accumulate ----
    ushort8v vr[KT];
#pragma unroll
    for (int k = 0; k < KT; ++k) {
        const int src = l - (KT - 1 - k) * dil;
        if (src >= 0)
            vr[k] = *(const ushort8v*)(qkv + rowbase + (size_t)src * NQKV
                                       + 8704 + k * HW);
    }

    float acc[8];
#pragma unroll
    for (int z = 0; z < 8; ++z) acc[z] = 0.f;
#pragma unroll
    for (int k = 0; k < KT; ++k) {
        const int src = l - (KT - 1 - k) * dil;
        const float sc = lg[k] * inv;
        if (src >= 0) {
#pragma unroll
            for (int z = 0; z < 8; ++z) acc[z] = fmaf(sc, bf2f(vr[k][z]), acc[z]);
        } else {
            const float* bvp = bv + hko + k * HW + (j << 3);
#pragma unroll
            for (int z = 0; z < 8; ++z) acc[z] = fmaf(sc, bvp[z], acc[z]);
        }
    }

    ushort8v o;
#pragma unroll
    for (int z = 0; z < 8; ++z) o[z] = f2bf(acc[z] * 0.125f);
    const int row = b * LL + l;
    const int k8 = h * 8 + j;
    const int sw = ((k8 & 3) ^ ((l >> 1) & 3)) << 3;
    *(ushort8v*)(attnb + (size_t)row * DM + ((k8 >> 2) << 5) + sw) = o;
}

// ===========================================================================
// ------------------- round-1 fp32 fallback (small ws) ----------------------
// ===========================================================================
__global__ __launch_bounds__(256, 2) void gemm_nt_bias(
    const float* __restrict__ A, const float* __restrict__ Bm,
    const float* __restrict__ bias, float* __restrict__ C,
    int M, int N, int Kd)
{
    __shared__ float As[16][68];
    __shared__ float Bs[16][68];
    const int tid = threadIdx.x;
    const int tx = tid & 15, ty = tid >> 4;
    const int r0 = blockIdx.y << 6, c0 = blockIdx.x << 6;
    const int lr = tid >> 2, k4 = (tid & 3) << 2;
    const float* Ap = A  + (size_t)(r0 + lr) * Kd + k4;
    const float* Bp = Bm + (size_t)(c0 + lr) * Kd + k4;
    float acc[4][4];
#pragma unroll
    for (int i = 0; i < 4; ++i)
#pragma unroll
        for (int j = 0; j < 4; ++j) acc[i][j] = 0.f;
    for (int d0 = 0; d0 < Kd; d0 += 16) {
        float4 av = *(const float4*)(Ap + d0);
        float4 bv = *(const float4*)(Bp + d0);
        As[k4 + 0][lr] = av.x; As[k4 + 1][lr] = av.y;
        As[k4 + 2][lr] = av.z; As[k4 + 3][lr] = av.w;
        Bs[k4 + 0][lr] = bv.x; Bs[k4 + 1][lr] = bv.y;
        Bs[k4 + 2][lr] = bv.z; Bs[k4 + 3][lr] = bv.w;
        __syncthreads();
#pragma unroll
        for (int dd = 0; dd < 16; ++dd) {
            float4 a4 = *(const float4*)&As[dd][ty << 2];
            float4 b4 = *(const float4*)&Bs[dd][tx << 2];
            float ar[4] = {a4.x, a4.y, a4.z, a4.w};
            float br[4] = {b4.x, b4.y, b4.z, b4.w};
#pragma unroll
            for (int i = 0; i < 4; ++i)
#pragma unroll
                for (int j = 0; j < 4; ++j)
                    acc[i][j] = fmaf(ar[i], br[j], acc[i][j]);
        }
        __syncthreads();
    }
#pragma unroll
    for (int i = 0; i < 4; ++i) {
        float4 o;
        const int c = c0 + (tx << 2);
        o.x = acc[i][0] + bias[c + 0];
        o.y = acc[i][1] + bias[c + 1];
        o.z = acc[i][2] + bias[c + 2];
        o.w = acc[i][3] + bias[c + 3];
        *(float4*)&C[(size_t)(r0 + (ty << 2) + i) * N + c] = o;
    }
}

__device__ __forceinline__ void tile_gemm_f32(
    const float* __restrict__ xb, int src, bool ok,
    const float* __restrict__ wrow,
    int lr, int k4, int tx, int ty,
    float (&As)[16][68], float (&Ws)[16][68], float (&acc)[4][4])
{
#pragma unroll
    for (int i = 0; i < 4; ++i)
#pragma unroll
        for (int j = 0; j < 4; ++j) acc[i][j] = 0.f;
    const float* xrow = xb + (size_t)(ok ? src : 0) * DM + k4;
    for (int d0 = 0; d0 < DM; d0 += 16) {
        float4 av = make_float4(0.f, 0.f, 0.f, 0.f);
        if (ok) av = *(const float4*)(xrow + d0);
        float4 wv = *(const float4*)(wrow + d0);
        As[k4 + 0][lr] = av.x; As[k4 + 1][lr] = av.y;
        As[k4 + 2][lr] = av.z; As[k4 + 3][lr] = av.w;
        Ws[k4 + 0][lr] = wv.x; Ws[k4 + 1][lr] = wv.y;
        Ws[k4 + 2][lr] = wv.z; Ws[k4 + 3][lr] = wv.w;
        __syncthreads();
#pragma unroll
        for (int dd = 0; dd < 16; ++dd) {
            float4 a4 = *(const float4*)&As[dd][ty << 2];
            float4 b4 = *(const float4*)&Ws[dd][tx << 2];
            float ar[4] = {a4.x, a4.y, a4.z, a4.w};
            float br[4] = {b4.x, b4.y, b4.z, b4.w};
#pragma unroll
            for (int i = 0; i < 4; ++i)
#pragma unroll
                for (int j = 0; j < 4; ++j)
                    acc[i][j] = fmaf(ar[i], br[j], acc[i][j]);
        }
        __syncthreads();
    }
}

__global__ __launch_bounds__(256, 2) void attn_kernel(
    const float* __restrict__ x, const float* __restrict__ q,
    const float* __restrict__ Wk, const float* __restrict__ bk,
    const float* __restrict__ Wv, const float* __restrict__ bv,
    float* __restrict__ attn)
{
    __shared__ float As[16][68];
    __shared__ float Ws[16][68];
    __shared__ float qs[64][68];
    __shared__ float lg[64][17];
    __shared__ float red[64][17];
    const int tid = threadIdx.x;
    const int tx = tid & 15, ty = tid >> 4;
    const int bid = blockIdx.x;
    const int h = bid & 7, t = (bid >> 3) & 15, b = bid >> 7;
    const int l0 = t << 6;
    const int dil = c_dil[h];
    const int lr = tid >> 2, k4 = (tid & 3) << 2;
    for (int i = tid; i < 64 * 16; i += 256) {
        int l = i >> 4, o4 = (i & 15) << 2;
        float4 v = *(const float4*)&q[((size_t)(b * LL + l0 + l) * HH + h) * HW + o4];
        *(float4*)&qs[l][o4] = v;
    }
    const float* xb  = x  + (size_t)b * LL * DM;
    const float* Wkh = Wk + (size_t)h * KT * HW * DM;
    const float* Wvh = Wv + (size_t)h * KT * HW * DM;
    const float* bkh = bk + h * KT * HW;
    const float* bvh = bv + h * KT * HW;
    float acc[4][4];
    for (int kk = 0; kk < KT; ++kk) {
        const int src = l0 + lr - (KT - 1 - kk) * dil;
        const bool ok = (src >= 0) && (src < LL);
        tile_gemm_f32(xb, src, ok, Wkh + (size_t)(kk * HW + lr) * DM + k4,
                      lr, k4, tx, ty, As, Ws, acc);
        const float* bkp = bkh + kk * HW + (tx << 2);
#pragma unroll
        for (int i = 0; i < 4; ++i) {
            float p = 0.f;
#pragma unroll
            for (int j = 0; j < 4; ++j)
                p += (acc[i][j] + bkp[j]) * qs[(ty << 2) + i][(tx << 2) + j];
            red[(ty << 2) + i][tx] = p;
        }
        __syncthreads();
        if (tid < 64) {
            float s = 0.f;
#pragma unroll
            for (int u = 0; u < 16; ++u) s += red[tid][u];
            lg[tid][kk] = s;
        }
        __syncthreads();
    }
    if (tid < 64) {
        float m = lg[tid][0];
#pragma unroll
        for (int u = 1; u < KT; ++u) m = fmaxf(m, lg[tid][u]);
        float s = 0.f;
#pragma unroll
        for (int u = 0; u < KT; ++u) {
            float e = expf(lg[tid][u] - m);
            lg[tid][u] = e; s += e;
        }
        float inv = 1.f / s;
#pragma unroll
        for (int u = 0; u < KT; ++u) lg[tid][u] *= inv;
    }
    __syncthreads();
    float vacc[4][4];
#pragma unroll
    for (int i = 0; i < 4; ++i)
#pragma unroll
        for (int j = 0; j < 4; ++j) vacc[i][j] = 0.f;
    for (int kk = 0; kk < KT; ++kk) {
        const int src = l0 + lr - (KT - 1 - kk) * dil;
        const bool ok = (src >= 0) && (src < LL);
        tile_gemm_f32(xb, src, ok, Wvh + (size_t)(kk * HW + lr) * DM + k4,
                      lr, k4, tx, ty, As, Ws, acc);
        const float* bvp = bvh + kk * HW + (tx << 2);
#pragma unroll
        for (int i = 0; i < 4; ++i) {
            float sc = lg[(ty << 2) + i][kk];
#pragma unroll
            for (int j = 0; j < 4; ++j)
                vacc[i][j] = fmaf(sc, acc[i][j] + bvp[j], vacc[i][j]);
        }
    }
#pragma unroll
    for (int i = 0; i < 4; ++i) {
        float4 o;
        o.x = vacc[i][0] * 0.125f;
        o.y = vacc[i][1] * 0.125f;
        o.z = vacc[i][2] * 0.125f;
        o.w = vacc[i][3] * 0.125f;
        *(float4*)&attn[((size_t)(b * LL + l0 + (ty << 2) + i) * HH + h) * HW + (tx << 2)] = o;
    }
}

// ===========================================================================
extern "C" void kernel_launch(void* const* d_in, const int* in_sizes, int n_in,
                              void* d_out, int out_size, void* d_ws, size_t ws_size,
                              hipStream_t stream)
{
    const float* x  = (const float*)d_in[0];
    const float* Wq = (const float*)d_in[1];
    const float* bq = (const float*)d_in[2];
    const float* Wk = (const float*)d_in[3];
    const float* bk = (const float*)d_in[4];
    const float* Wv = (const float*)d_in[5];
    const float* bv = (const float*)d_in[6];
    const float* Wo = (const float*)d_in[7];
    const float* bo = (const float*)d_in[8];
    float* out = (float*)d_out;

    const int M = BD * LL;  // 2048

    // ws layout (ushort elements) for the fast path
    const size_t N_X   = (size_t)BD * LL * DM;            //  1,048,576
    const size_t N_WB  = (size_t)NQKV * DM;               //  8,650,752
    const size_t N_WO  = (size_t)DM * DM;                 //    262,144
    const size_t N_QKV = (size_t)M * NQKV;                // 34,603,008
    const size_t NEED  = (N_X + N_WB + N_WO + N_QKV + N_X) * 2;

    if (ws_size >= NEED) {
        u16* xb    = (u16*)d_ws;
        u16* wb    = xb    + N_X;      // [Wq|Wk|Wv] swizzled, 16896 x 512
        u16* wob   = wb    + N_WB;
        u16* qkv   = wob   + N_WO;     // natural row-major 2048 x 16896
        u16* attnb = qkv   + N_QKV;

        cvt_swz<<<4864, 256, 0, stream>>>(x, Wq, Wk, Wv, Wo, xb, wb, wob);

        // qkv = x * [Wq|Wk|Wv]^T + bias (2-phase double-buffered)
        gemm_bf16<<<dim3(136, 16), 256, 0, stream>>>(
            xb, wb, bq, bk, bv, qkv);

        // two-phase register-resident gather -> attnb (swizzled)
        attn_bf16<<<BD * HH * (LL / 32), 256, 0, stream>>>(
            qkv, bk, bv, attnb);

        // out = attnb * Wo^T + bo -> fp32
        gemm_out<<<dim3(8, 32), 256, 0, stream>>>(attnb, wob, bo, out);
    } else {
        // fp32 fallback (round-1 path, 8 MB ws)
        float* qws = (float*)d_ws;
        float* aws = qws + (size_t)BD * LL * HH * HW;
        gemm_nt_bias<<<dim3((HH * HW) / 64, M / 64), 256, 0, stream>>>(
            x, Wq, bq, qws, M, HH * HW, DM);
        attn_kernel<<<BD * HH * (LL / 64), 256, 0, stream>>>(
            x, qws, Wk, bk, Wv, bv, aws);
        gemm_nt_bias<<<dim3(DM / 64, M / 64), 256, 0, stream>>>(
            aws, Wo, bo, out, M, DM, HH * HW);
    }
}

// Round 4
// 171.501 us; speedup vs baseline: 1.0570x; 1.0025x over previous
//
#include <hip/hip_runtime.h>

// LCSA: dilated local-window self-attention.
// B=2, L=1024, D=512, H=8, HEAD_W=64, KERNEL=16, dilations {1,1,2,2,4,4,8,8},
// MODE=forward -> src(l,k) = l - (15-k)*dil, zero-padded outside [0,L).
//
// R13: gemm_bf16 = R12 structure (128x128, BK=32, 2-phase dbuf, 4 blk/CU)
//   + XCD-chunked bijective block remap, m-fastest-within-XCD:
//   R10/R12 both stuck ~57-62us @ MfmaUtil 23% because grid (136,16)
//   round-robins n-panels across XCDs: ~128 concurrent blocks/XCD x distinct
//   128KB B-panels = 16MB live set vs 4MB XCD L2 -> B reuse (277MB) misses
//   to L3 at ~450cyc, unhideable. Remap wg=(bid&7)*264+(bid>>3), m fastest:
//   per-XCD live set = 8 B-panels (1MB) + 16 A-panels (2MB) = 3MB < 4MB L2.
//   Grid 2112 linear (132x16 exact, no pad-exit).
// attn_bf16: TWO-PHASE register-resident gather (unchanged, R10).
// cvt_swz:   fp32->bf16 + per-row XOR chunk swizzle (unchanged, R10).
// gemm_out:  2-phase dbuf (unchanged, R12).
// Fallback:  round-1 fp32 path (8 MB ws).

#define BD 2
#define LL 1024
#define DM 512
#define HH 8
#define KT 16
#define HW 64

#define NQKV 16896          // 512 q + 8192 k + 8192 v

typedef unsigned short u16;
typedef unsigned int u32;
typedef __bf16 bf16x8 __attribute__((ext_vector_type(8)));
typedef float f32x4 __attribute__((ext_vector_type(4)));
typedef unsigned short ushort4v __attribute__((ext_vector_type(4)));
typedef unsigned short ushort8v __attribute__((ext_vector_type(8)));

__constant__ int c_dil[8] = {1, 1, 2, 2, 4, 4, 8, 8};

__device__ __forceinline__ float bf2f(u16 u) {
    return __builtin_bit_cast(float, (u32)u << 16);
}
__device__ __forceinline__ u16 f2bf(float f) {   // round-to-nearest-even
    u32 u = __builtin_bit_cast(u32, f);
    return (u16)((u + 0x7fffu + ((u >> 16) & 1u)) >> 16);
}

// async global->LDS, 16 B per lane; lds dest must be (uniform base + lane*16)
__device__ __forceinline__ void gl_lds16(const u16* g, u16* l) {
    __builtin_amdgcn_global_load_lds(
        (__attribute__((address_space(1))) void*)g,
        (__attribute__((address_space(3))) void*)l, 16, 0, 0);
}

// ===========================================================================
// Fused qkv projection GEMM, 2-phase double-buffered, XCD-chunked.
// C(2048 x NQKV bf16) = x(2048x512) * [Wq|Wk|Wv]^T + bias.
// 128x128 tile, BK=32, 4 waves (64x64 each), 16x16x32 MFMA, swizzled A/B,
// LDS 32KB (2 bufs) -> 4 blocks/CU. Grid 2112 linear.
//
// Block remap: wg = (bid&7)*264 + (bid>>3)  (bijective, 2112 = 8*264).
//   m0 = (wg&15)*128 (fastest within XCD), n0 = (wg>>4)*128.
//   -> per-XCD concurrent set: ~8 consecutive B-panels + all 16 A-panels,
//      3MB, L2-resident. B-panel reuse (16x) now hits XCD L2.
//
// Per iter: issue 4 gl_lds16 for tile t+1 into buf^1 (no wait), ds_read
// buf, 16 MFMA, then ONE __syncthreads (drains vmcnt: t+1 landed; also
// retires all waves' ds_reads of buf before next iter overwrites it).
// ===========================================================================
__global__ __launch_bounds__(256, 4) void gemm_bf16(
    const u16* __restrict__ A, const u16* __restrict__ Bm,
    const float* __restrict__ bq, const float* __restrict__ bk,
    const float* __restrict__ bv, u16* __restrict__ C)
{
    // XCD-chunked bijective remap (8 XCDs, 2112 = 8*264 blocks)
    const int bid = blockIdx.x;
    const int wg  = (bid & 7) * 264 + (bid >> 3);
    const int m0  = (wg & 15) << 7;     // m fastest within an XCD
    const int n0  = (wg >> 4) << 7;     // 132 n-tiles of 128

    __shared__ u16 As[2][128 * 32];     // 2 x 8 KB
    __shared__ u16 Bs[2][128 * 32];     // 2 x 8 KB

    const int tid  = threadIdx.x;
    const int wave = tid >> 6, lane = tid & 63;
    const int r0 = tid >> 2;            // staging row 0..63 (round 0)
    const int cc = (tid & 3) << 3;      // staging k-offset (elements)
    const int mw = (wave >> 1) << 6;
    const int nw = (wave & 1) << 6;
    const int lr = lane & 15;
    const int qg = lane >> 4;
    const int ksw = ((qg ^ ((lr >> 1) & 3)) << 3);   // swizzled chunk

    const u16* Ag = A  + (size_t)(m0 + r0) * DM + cc;
    const u16* Bg = Bm + (size_t)(n0 + r0) * DM + cc;
    u16* lA = &As[0][0] + tid * 8;
    u16* lB = &Bs[0][0] + tid * 8;

    // stage k-chunk at element offset ko into buffer c (4 loads/thread)
#define STG(ko, c) do {                                                    \
        gl_lds16(Ag + (ko),                  lA + (c) * 4096);             \
        gl_lds16(Ag + (ko) + (size_t)64*DM,  lA + (c) * 4096 + 2048);      \
        gl_lds16(Bg + (ko),                  lB + (c) * 4096);             \
        gl_lds16(Bg + (ko) + (size_t)64*DM,  lB + (c) * 4096 + 2048);      \
    } while (0)

    f32x4 acc[4][4];
#pragma unroll
    for (int i = 0; i < 4; ++i)
#pragma unroll
        for (int j = 0; j < 4; ++j) acc[i][j] = (f32x4){0.f, 0.f, 0.f, 0.f};

    STG(0, 0);
    __syncthreads();                    // tile 0 resident

#pragma unroll
    for (int kc = 0; kc < 16; ++kc) {
        const int cur = kc & 1;
        if (kc < 15) STG((kc + 1) << 5, cur ^ 1);   // prefetch next tile

        bf16x8 af[4], bfr[4];
#pragma unroll
        for (int i = 0; i < 4; ++i)
            af[i] = *(const bf16x8*)&As[cur][(mw + (i << 4) + lr) * 32 + ksw];
#pragma unroll
        for (int j = 0; j < 4; ++j)
            bfr[j] = *(const bf16x8*)&Bs[cur][(nw + (j << 4) + lr) * 32 + ksw];
#pragma unroll
        for (int i = 0; i < 4; ++i)
#pragma unroll
            for (int j = 0; j < 4; ++j)
                acc[i][j] = __builtin_amdgcn_mfma_f32_16x16x32_bf16(
                    af[i], bfr[j], acc[i][j], 0, 0, 0);

        __syncthreads();                // drains vmcnt: tile kc+1 landed;
                                        // all reads of buf[cur] retired
    }
#undef STG

    // bias region is tile-uniform (n-tiles 0..3 q, 4..67 k, 68..131 v)
    const float* bias; int cb;
    if      (n0 <  512) { bias = bq; cb = 0;    }
    else if (n0 < 8704) { bias = bk; cb = 512;  }
    else                { bias = bv; cb = 8704; }

    // C row = m0+mw+16i+4qg+r, col = n0+nw+16j+lr
#pragma unroll
    for (int i = 0; i < 4; ++i) {
        const int rowb = m0 + mw + (i << 4) + (qg << 2);
#pragma unroll
        for (int j = 0; j < 4; ++j) {
            const int col = n0 + nw + (j << 4) + lr;
            const float bs = bias[col - cb];
#pragma unroll
            for (int r = 0; r < 4; ++r)
                C[(size_t)(rowb + r) * NQKV + col] = f2bf(acc[i][j][r] + bs);
        }
    }
}

// ===========================================================================
// Output projection: out(2048x512 fp32) = attnb(2048x512 swz) * Wo^T(512x512
// swz) + bo. 64x64 tiles, grid (8,32) = 256 blocks, 4 waves (16x64 each).
// 2-phase double-buffered (R12).
// ===========================================================================
__global__ __launch_bounds__(256, 4) void gemm_out(
    const u16* __restrict__ A, const u16* __restrict__ Bm,
    const float* __restrict__ bias, float* __restrict__ C)
{
    __shared__ u16 As[2][64 * 32];      // 2 x 4 KB
    __shared__ u16 Bs[2][64 * 32];      // 2 x 4 KB

    const int tid  = threadIdx.x;
    const int wave = tid >> 6, lane = tid & 63;
    const int m0 = blockIdx.y << 6, n0 = blockIdx.x << 6;
    const int r0 = tid >> 2, cc = (tid & 3) << 3;
    const int mw = wave << 4;           // wave's 16-row band
    const int lr = lane & 15, qg = lane >> 4;
    const int ksw = ((qg ^ ((lr >> 1) & 3)) << 3);

    const u16* Ag = A  + (size_t)(m0 + r0) * DM + cc;
    const u16* Bg = Bm + (size_t)(n0 + r0) * DM + cc;
    u16* lA = &As[0][0] + tid * 8;
    u16* lB = &Bs[0][0] + tid * 8;

#define STG(ko, c) do {                                                    \
        gl_lds16(Ag + (ko), lA + (c) * 2048);                              \
        gl_lds16(Bg + (ko), lB + (c) * 2048);                              \
    } while (0)

    f32x4 acc[4];
#pragma unroll
    for (int j = 0; j < 4; ++j) acc[j] = (f32x4){0.f, 0.f, 0.f, 0.f};

    STG(0, 0);
    __syncthreads();

#pragma unroll
    for (int kc = 0; kc < 16; ++kc) {
        const int cur = kc & 1;
        if (kc < 15) STG((kc + 1) << 5, cur ^ 1);

        bf16x8 af = *(const bf16x8*)&As[cur][(mw + lr) * 32 + ksw];
#pragma unroll
        for (int j = 0; j < 4; ++j) {
            bf16x8 bfr = *(const bf16x8*)&Bs[cur][((j << 4) + lr) * 32 + ksw];
            acc[j] = __builtin_amdgcn_mfma_f32_16x16x32_bf16(af, bfr, acc[j], 0, 0, 0);
        }
        __syncthreads();
    }
#undef STG

    // C row = m0+mw+4qg+r, col = n0+16j+lr
#pragma unroll
    for (int j = 0; j < 4; ++j) {
        const int col = n0 + (j << 4) + lr;
        const float bs = bias[col];
#pragma unroll
        for (int r = 0; r < 4; ++r)
            C[(size_t)(m0 + mw + (qg << 2) + r) * DM + col] = acc[j][r] + bs;
    }
}

// ===========================================================================
// fp32 -> bf16 + swizzle. One thread per 8-elem chunk: 32B read, 16B write,
// both coalesced (the XOR permutes chunks within a 64B line).
// Chunks (row*64): x 131072 | [Wq|Wk|Wv] 1081344 | Wo 32768
// Total 1245184 = 4864 blocks x 256.
// ===========================================================================
__global__ void cvt_swz(const float* __restrict__ x,  const float* __restrict__ Wq,
                        const float* __restrict__ Wk, const float* __restrict__ Wv,
                        const float* __restrict__ Wo,
                        u16* __restrict__ xb, u16* __restrict__ wb,
                        u16* __restrict__ wob)
{
    const int i = blockIdx.x * 256 + threadIdx.x;
    const float* src; u16* dst; int t;
    if (i < 131072) {
        t = i;
        src = x;  dst = xb;
    } else if (i < 1212416) {
        t = i - 131072;
        const int row = t >> 6;
        if      (row <  512) src = Wq;
        else if (row < 8704) src = Wk - (size_t)512 * DM;
        else                 src = Wv - (size_t)8704 * DM;
        dst = wb;
    } else {
        t = i - 1212416;
        src = Wo; dst = wob;
    }
    const int row = t >> 6;              // 64 chunks per row
    const int c8  = t & 63;              // output chunk within row
    const int s   = (row >> 1) & 3;
    const int oc  = (c8 & ~3) | ((c8 & 3) ^ s);   // source chunk
    const float* p = src + (size_t)row * DM + (oc << 3);
    float4 v0 = *(const float4*)p;
    float4 v1 = *(const float4*)(p + 4);
    ushort8v o = { f2bf(v0.x), f2bf(v0.y), f2bf(v0.z), f2bf(v0.w),
                   f2bf(v1.x), f2bf(v1.y), f2bf(v1.z), f2bf(v1.w) };
    *(ushort8v*)(dst + (size_t)row * DM + (c8 << 3)) = o;
}

// ===========================================================================
// attention gather, TWO-PHASE register-resident.
// 256 thr = 32 l's x 8 o-groups, grid = B*H*(L/32) = 512.
// Phase 1: all 16 k-row loads issued back-to-back (independent addresses,
//          max loads-in-flight), 16 logits via 3x shfl_xor each.
// Softmax entirely in registers.
// Phase 2: all 16 v-row loads issued, weighted accumulate.
// (256,4) -> 128-VGPR budget: kr[16] payload is 64 VGPRs; R9's (256,8)
// forced VGPR=32 and serialized the stream (65us @ 28% HBM).
// ===========================================================================
__global__ __launch_bounds__(256, 4) void attn_bf16(
    const u16* __restrict__ qkv,    // (B*L, NQKV) bf16
    const float* __restrict__ bk,   // (H,K,64) fp32
    const float* __restrict__ bv,
    u16* __restrict__ attnb)        // (B,L,512) bf16 swizzled
{
    const int tid = threadIdx.x;
    const int j  = tid & 7;          // o-group (8 o's)
    const int ll = tid >> 3;         // 0..31
    const int bid = blockIdx.x;
    const int h = bid & 7;
    const int t = (bid >> 3) & 31;
    const int b = bid >> 8;
    const int l = (t << 5) + ll;
    const int dil = c_dil[h];

    const int hko = h * (KT * HW);   // head offset within k/v region
    const size_t rowbase = (size_t)(b * LL) * NQKV + hko + (j << 3);

    float qf[8];
    {
        ushort8v qv = *(const ushort8v*)(qkv + (size_t)(b * LL + l) * NQKV
                                         + h * HW + (j << 3));
#pragma unroll
        for (int z = 0; z < 8; ++z) qf[z] = bf2f(qv[z]);
    }

    // ---- phase 1: all k loads in flight, then logits ----
    ushort8v kr[KT];
#pragma unroll
    for (int k = 0; k < KT; ++k) {
        const int src = l - (KT - 1 - k) * dil;
        if (src >= 0)
            kr[k] = *(const ushort8v*)(qkv + rowbase + (size_t)src * NQKV
                                       + 512 + k * HW);
    }

    float lg[KT];
#pragma unroll
    for (int k = 0; k < KT; ++k) {
        const int src = l - (KT - 1 - k) * dil;
        float p = 0.f;
        if (src >= 0) {
#pragma unroll
            for (int z = 0; z < 8; ++z) p += qf[z] * bf2f(kr[k][z]);
        } else {
            const float* bkp = bk + hko + k * HW + (j << 3);
#pragma unroll
            for (int z = 0; z < 8; ++z) p += qf[z] * bkp[z];
        }
        p += __shfl_xor(p, 1);
        p += __shfl_xor(p, 2);
        p += __shfl_xor(p, 4);
        lg[k] = p;
    }

    // ---- softmax in registers ----
    float m = lg[0];
#pragma unroll
    for (int k = 1; k < KT; ++k) m = fmaxf(m, lg[k]);
    float s = 0.f;
#pragma unroll
    for (int k = 0; k < KT; ++k) { lg[k] = __expf(lg[k] - m); s += lg[k]; }
    const float inv = 1.f / s;

    // ---- phase 2: all v loads in flight, weighted accumulate ----
    ushort8v vr[KT];
#pragma unroll
    for (int k = 0; k < KT; ++k) {
        const int src = l - (KT - 1 - k) * dil;
        if (src >= 0)
            vr[k] = *(const ushort8v*)(qkv + rowbase + (size_t)src * NQKV
                                       + 8704 + k * HW);
    }

    float acc[8];
#pragma unroll
    for (int z = 0; z < 8; ++z) acc[z] = 0.f;
#pragma unroll
    for (int k = 0; k < KT; ++k) {
        const int src = l - (KT - 1 - k) * dil;
        const float sc = lg[k] * inv;
        if (src >= 0) {
#pragma unroll
            for (int z = 0; z < 8; ++z) acc[z] = fmaf(sc, bf2f(vr[k][z]), acc[z]);
        } else {
            const float* bvp = bv + hko + k * HW + (j << 3);
#pragma unroll
            for (int z = 0; z < 8; ++z) acc[z] = fmaf(sc, bvp[z], acc[z]);
        }
    }

    ushort8v o;
#pragma unroll
    for (int z = 0; z < 8; ++z) o[z] = f2bf(acc[z] * 0.125f);
    const int row = b * LL + l;
    const int k8 = h * 8 + j;
    const int sw = ((k8 & 3) ^ ((l >> 1) & 3)) << 3;
    *(ushort8v*)(attnb + (size_t)row * DM + ((k8 >> 2) << 5) + sw) = o;
}

// ===========================================================================
// ------------------- round-1 fp32 fallback (small ws) ----------------------
// ===========================================================================
__global__ __launch_bounds__(256, 2) void gemm_nt_bias(
    const float* __restrict__ A, const float* __restrict__ Bm,
    const float* __restrict__ bias, float* __restrict__ C,
    int M, int N, int Kd)
{
    __shared__ float As[16][68];
    __shared__ float Bs[16][68];
    const int tid = threadIdx.x;
    const int tx = tid & 15, ty = tid >> 4;
    const int r0 = blockIdx.y << 6, c0 = blockIdx.x << 6;
    const int lr = tid >> 2, k4 = (tid & 3) << 2;
    const float* Ap = A  + (size_t)(r0 + lr) * Kd + k4;
    const float* Bp = Bm + (size_t)(c0 + lr) * Kd + k4;
    float acc[4][4];
#pragma unroll
    for (int i = 0; i < 4; ++i)
#pragma unroll
        for (int j = 0; j < 4; ++j) acc[i][j] = 0.f;
    for (int d0 = 0; d0 < Kd; d0 += 16) {
        float4 av = *(const float4*)(Ap + d0);
        float4 bv = *(const float4*)(Bp + d0);
        As[k4 + 0][lr] = av.x; As[k4 + 1][lr] = av.y;
        As[k4 + 2][lr] = av.z; As[k4 + 3][lr] = av.w;
        Bs[k4 + 0][lr] = bv.x; Bs[k4 + 1][lr] = bv.y;
        Bs[k4 + 2][lr] = bv.z; Bs[k4 + 3][lr] = bv.w;
        __syncthreads();
#pragma unroll
        for (int dd = 0; dd < 16; ++dd) {
            float4 a4 = *(const float4*)&As[dd][ty << 2];
            float4 b4 = *(const float4*)&Bs[dd][tx << 2];
            float ar[4] = {a4.x, a4.y, a4.z, a4.w};
            float br[4] = {b4.x, b4.y, b4.z, b4.w};
#pragma unroll
            for (int i = 0; i < 4; ++i)
#pragma unroll
                for (int j = 0; j < 4; ++j)
                    acc[i][j] = fmaf(ar[i], br[j], acc[i][j]);
        }
        __syncthreads();
    }
#pragma unroll
    for (int i = 0; i < 4; ++i) {
        float4 o;
        const int c = c0 + (tx << 2);
        o.x = acc[i][0] + bias[c + 0];
        o.y = acc[i][1] + bias[c + 1];
        o.z = acc[i][2] + bias[c + 2];
        o.w = acc[i][3] + bias[c + 3];
        *(float4*)&C[(size_t)(r0 + (ty << 2) + i) * N + c] = o;
    }
}

__device__ __forceinline__ void tile_gemm_f32(
    const float* __restrict__ xb, int src, bool ok,
    const float* __restrict__ wrow,
    int lr, int k4, int tx, int ty,
    float (&As)[16][68], float (&Ws)[16][68], float (&acc)[4][4])
{
#pragma unroll
    for (int i = 0; i < 4; ++i)
#pragma unroll
        for (int j = 0; j < 4; ++j) acc[i][j] = 0.f;
    const float* xrow = xb + (size_t)(ok ? src : 0) * DM + k4;
    for (int d0 = 0; d0 < DM; d0 += 16) {
        float4 av = make_float4(0.f, 0.f, 0.f, 0.f);
        if (ok) av = *(const float4*)(xrow + d0);
        float4 wv = *(const float4*)(wrow + d0);
        As[k4 + 0][lr] = av.x; As[k4 + 1][lr] = av.y;
        As[k4 + 2][lr] = av.z; As[k4 + 3][lr] = av.w;
        Ws[k4 + 0][lr] = wv.x; Ws[k4 + 1][lr] = wv.y;
        Ws[k4 + 2][lr] = wv.z; Ws[k4 + 3][lr] = wv.w;
        __syncthreads();
#pragma unroll
        for (int dd = 0; dd < 16; ++dd) {
            float4 a4 = *(const float4*)&As[dd][ty << 2];
            float4 b4 = *(const float4*)&Ws[dd][tx << 2];
            float ar[4] = {a4.x, a4.y, a4.z, a4.w};
            float br[4] = {b4.x, b4.y, b4.z, b4.w};
#pragma unroll
            for (int i = 0; i < 4; ++i)
#pragma unroll
                for (int j = 0; j < 4; ++j)
                    acc[i][j] = fmaf(ar[i], br[j], acc[i][j]);
        }
        __syncthreads();
    }
}

__global__ __launch_bounds__(256, 2) void attn_kernel(
    const float* __restrict__ x, const float* __restrict__ q,
    const float* __restrict__ Wk, const float* __restrict__ bk,
    const float* __restrict__ Wv, const float* __restrict__ bv,
    float* __restrict__ attn)
{
    __shared__ float As[16][68];
    __shared__ float Ws[16][68];
    __shared__ float qs[64][68];
    __shared__ float lg[64][17];
    __shared__ float red[64][17];
    const int tid = threadIdx.x;
    const int tx = tid & 15, ty = tid >> 4;
    const int bid = blockIdx.x;
    const int h = bid & 7, t = (bid >> 3) & 15, b = bid >> 7;
    const int l0 = t << 6;
    const int dil = c_dil[h];
    const int lr = tid >> 2, k4 = (tid & 3) << 2;
    for (int i = tid; i < 64 * 16; i += 256) {
        int l = i >> 4, o4 = (i & 15) << 2;
        float4 v = *(const float4*)&q[((size_t)(b * LL + l0 + l) * HH + h) * HW + o4];
        *(float4*)&qs[l][o4] = v;
    }
    const float* xb  = x  + (size_t)b * LL * DM;
    const float* Wkh = Wk + (size_t)h * KT * HW * DM;
    const float* Wvh = Wv + (size_t)h * KT * HW * DM;
    const float* bkh = bk + h * KT * HW;
    const float* bvh = bv + h * KT * HW;
    float acc[4][4];
    for (int kk = 0; kk < KT; ++kk) {
        const int src = l0 + lr - (KT - 1 - kk) * dil;
        const bool ok = (src >= 0) && (src < LL);
        tile_gemm_f32(xb, src, ok, Wkh + (size_t)(kk * HW + lr) * DM + k4,
                      lr, k4, tx, ty, As, Ws, acc);
        const float* bkp = bkh + kk * HW + (tx << 2);
#pragma unroll
        for (int i = 0; i < 4; ++i) {
            float p = 0.f;
#pragma unroll
            for (int j = 0; j < 4; ++j)
                p += (acc[i][j] + bkp[j]) * qs[(ty << 2) + i][(tx << 2) + j];
            red[(ty << 2) + i][tx] = p;
        }
        __syncthreads();
        if (tid < 64) {
            float s = 0.f;
#pragma unroll
            for (int u = 0; u < 16; ++u) s += red[tid][u];
            lg[tid][kk] = s;
        }
        __syncthreads();
    }
    if (tid < 64) {
        float m = lg[tid][0];
#pragma unroll
        for (int u = 1; u < KT; ++u) m = fmaxf(m, lg[tid][u]);
        float s = 0.f;
#pragma unroll
        for (int u = 0; u < KT; ++u) {
            float e = expf(lg[tid][u] - m);
            lg[tid][u] = e; s += e;
        }
        float inv = 1.f / s;
#pragma unroll
        for (int u = 0; u < KT; ++u) lg[tid][u] *= inv;
    }
    __syncthreads();
    float vacc[4][4];
#pragma unroll
    for (int i = 0; i < 4; ++i)
#pragma unroll
        for (int j = 0; j < 4; ++j) vacc[i][j] = 0.f;
    for (int kk = 0; kk < KT; ++kk) {
        const int src = l0 + lr - (KT - 1 - kk) * dil;
        const bool ok = (src >= 0) && (src < LL);
        tile_gemm_f32(xb, src, ok, Wvh + (size_t)(kk * HW + lr) * DM + k4,
                      lr, k4, tx, ty, As, Ws, acc);
        const float* bvp = bvh + kk * HW + (tx << 2);
#pragma unroll
        for (int i = 0; i < 4; ++i) {
            float sc = lg[(ty << 2) + i][kk];
#pragma unroll
            for (int j = 0; j < 4; ++j)
                vacc[i][j] = fmaf(sc, acc[i][j] + bvp[j], vacc[i][j]);
        }
    }
#pragma unroll
    for (int i = 0; i < 4; ++i) {
        float4 o;
        o.x = vacc[i][0] * 0.125f;
        o.y = vacc[i][1] * 0.125f;
        o.z = vacc[i][2] * 0.125f;
        o.w = vacc[i][3] * 0.125f;
        *(float4*)&attn[((size_t)(b * LL + l0 + (ty << 2) + i) * HH + h) * HW + (tx << 2)] = o;
    }
}

// ===========================================================================
extern "C" void kernel_launch(void* const* d_in, const int* in_sizes, int n_in,
                              void* d_out, int out_size, void* d_ws, size_t ws_size,
                              hipStream_t stream)
{
    const float* x  = (const float*)d_in[0];
    const float* Wq = (const float*)d_in[1];
    const float* bq = (const float*)d_in[2];
    const float* Wk = (const float*)d_in[3];
    const float* bk = (const float*)d_in[4];
    const float* Wv = (const float*)d_in[5];
    const float* bv = (const float*)d_in[6];
    const float* Wo = (const float*)d_in[7];
    const float* bo = (const float*)d_in[8];
    float* out = (float*)d_out;

    const int M = BD * LL;  // 2048

    // ws layout (ushort elements) for the fast path
    const size_t N_X   = (size_t)BD * LL * DM;            //  1,048,576
    const size_t N_WB  = (size_t)NQKV * DM;               //  8,650,752
    const size_t N_WO  = (size_t)DM * DM;                 //    262,144
    const size_t N_QKV = (size_t)M * NQKV;                // 34,603,008
    const size_t NEED  = (N_X + N_WB + N_WO + N_QKV + N_X) * 2;

    if (ws_size >= NEED) {
        u16* xb    = (u16*)d_ws;
        u16* wb    = xb    + N_X;      // [Wq|Wk|Wv] swizzled, 16896 x 512
        u16* wob   = wb    + N_WB;
        u16* qkv   = wob   + N_WO;     // natural row-major 2048 x 16896
        u16* attnb = qkv   + N_QKV;

        cvt_swz<<<4864, 256, 0, stream>>>(x, Wq, Wk, Wv, Wo, xb, wb, wob);

        // qkv = x * [Wq|Wk|Wv]^T + bias (2-phase dbuf, XCD-chunked remap)
        gemm_bf16<<<dim3(2112), 256, 0, stream>>>(
            xb, wb, bq, bk, bv, qkv);

        // two-phase register-resident gather -> attnb (swizzled)
        attn_bf16<<<BD * HH * (LL / 32), 256, 0, stream>>>(
            qkv, bk, bv, attnb);

        // out = attnb * Wo^T + bo -> fp32
        gemm_out<<<dim3(8, 32), 256, 0, stream>>>(attnb, wob, bo, out);
    } else {
        // fp32 fallback (round-1 path, 8 MB ws)
        float* qws = (float*)d_ws;
        float* aws = qws + (size_t)BD * LL * HH * HW;
        gemm_nt_bias<<<dim3((HH * HW) / 64, M / 64), 256, 0, stream>>>(
            x, Wq, bq, qws, M, HH * HW, DM);
        attn_kernel<<<BD * HH * (LL / 64), 256, 0, stream>>>(
            x, qws, Wk, bk, Wv, bv, aws);
        gemm_nt_bias<<<dim3(DM / 64, M / 64), 256, 0, stream>>>(
            aws, Wo, bo, out, M, DM, HH * HW);
    }
}